// Round 1
// baseline (190.056 us; speedup 1.0000x reference)
//
#include <hip/hip_runtime.h>

// MPS classifier chain: logits[b,o] = (v/||v||)·cls[o] + log||v||,
//   v = head0(b) · M_1(b) · ... · M_783(b),  M_n = (1-x[b,n])*A_n + x[b,n]*B_n.
// Any contraction order is mathematically identical to the reference's
// pairwise tree (normalization scalars telescope), so we evaluate the chain
// sequentially per sample with renorm every 4 sites.
//
// Parallel structure: 16 lanes per sample (lanes j<10 active as matrix
// columns), 4 samples per 64-thread block (1 wave). h replicated in all
// lanes of the group via __shfl broadcast after each site.

constexpr int Bsz = 2048;
constexpr int Nn  = 784;   // sites incl. head
constexpr int Dd  = 10;

__global__ __launch_bounds__(64, 1) void mps_chain_kernel(
    const float* __restrict__ x,       // (B, 784)
    const float* __restrict__ core0,   // (1, 2, 10) -> [f*10 + h]
    const float* __restrict__ cores,   // (783, 10, 2, 10) -> [n*200 + l*20 + f*10 + h]
    const float* __restrict__ cls,     // (10, 10) -> [o*10 + d]
    float* __restrict__ out)           // (B, 10)
{
    const int lane  = threadIdx.x;        // 0..63
    const int j     = lane & 15;          // column index within group
    const int jj    = (j < Dd) ? j : (Dd - 1);  // clamp idle lanes' load addr (stay in bounds)
    const int gbase = lane & 48;          // group base lane in wave
    const int samp  = (int)blockIdx.x * 4 + (lane >> 4);
    if (samp >= Bsz) return;

    const float* __restrict__ xb = x + (size_t)samp * Nn;

    // init head, replicated in all lanes
    float h[Dd];
    {
        const float x0 = xb[0];
#pragma unroll
        for (int i = 0; i < Dd; ++i) {
            const float f0 = core0[i];
            const float f1 = core0[Dd + i];
            h[i] = fmaf(x0, f1 - f0, f0);
        }
    }

    float llog = 0.0f;   // accumulates log(s), s = squared norm chains

    for (int n = 1; n < Nn; ++n) {
        const float* __restrict__ W = cores + (size_t)(n - 1) * 200 + jj;
        const float xv = xb[n];

        // lane j computes column j of h' = h * ((1-x)*A + x*B)
        float cA = 0.0f, cB = 0.0f;
#pragma unroll
        for (int i = 0; i < Dd; ++i) {
            cA = fmaf(h[i], W[i * 20], cA);        // A[i][j]
            cB = fmaf(h[i], W[i * 20 + Dd], cB);   // B[i][j]
        }
        const float hn = fmaf(xv, cB - cA, cA);

        // broadcast new h to all lanes of the 16-lane group
#pragma unroll
        for (int i = 0; i < Dd; ++i)
            h[i] = __shfl(hn, gbase + i);

        // renormalize every 4 sites (and at the final site)
        if ((n & 3) == 0 || n == Nn - 1) {
            float s = 0.0f;
#pragma unroll
            for (int i = 0; i < Dd; ++i) s = fmaf(h[i], h[i], s);
            s = fmaxf(s, 1e-30f);
            const float r = rsqrtf(s);
            llog += __logf(s);
#pragma unroll
            for (int i = 0; i < Dd; ++i) h[i] *= r;
        }
    }

    // epilogue: lane o<10 computes logit[samp, o]
    if (j < Dd) {
        const float* __restrict__ crow = cls + j * Dd;
        float acc = 0.5f * llog;   // log_norm = 0.5 * sum(log(s))
#pragma unroll
        for (int i = 0; i < Dd; ++i) acc = fmaf(h[i], crow[i], acc);
        out[(size_t)samp * Dd + j] = acc;
    }
}

extern "C" void kernel_launch(void* const* d_in, const int* in_sizes, int n_in,
                              void* d_out, int out_size, void* d_ws, size_t ws_size,
                              hipStream_t stream) {
    const float* x     = (const float*)d_in[0];
    const float* core0 = (const float*)d_in[1];
    const float* cores = (const float*)d_in[2];
    const float* cls   = (const float*)d_in[3];
    float* out = (float*)d_out;

    const int groups_per_block = 4;                 // 4 samples per 64-thread block
    const int grid = Bsz / groups_per_block;        // 512 blocks
    hipLaunchKernelGGL(mps_chain_kernel, dim3(grid), dim3(64), 0, stream,
                       x, core0, cores, cls, out);
}